// Round 5
// baseline (932.471 us; speedup 1.0000x reference)
//
#include <hip/hip_runtime.h>
#include <math.h>

#define G 4
#define NN 50000
#define EE 400000
#define D 128
#define LN_EPS 1e-5f
#define BPG 782    // blocks per graph (782*64 >= 50000)
#define SM 50008   // per-graph stride of E array in ints (NN+1 padded to 8)
#define CH 2048    // scan chunk (entries per block)
#define NCH ((NN + CH - 1) / CH)  // 25 chunks per graph

typedef _Float16 f16;
typedef _Float16 f16x4 __attribute__((ext_vector_type(4)));
typedef _Float16 f16x8 __attribute__((ext_vector_type(8)));
typedef float f32x4 __attribute__((ext_vector_type(4)));

// ---------------- CSR build ----------------

__global__ __launch_bounds__(256) void hist_kernel(const int* __restrict__ ei, int* __restrict__ deg) {
    int idx = blockIdx.x * 256 + threadIdx.x;
    if (idx >= G * EE) return;
    int g = idx / EE, e = idx - g * EE;
    int dst = ei[g * 2 * EE + EE + e];
    atomicAdd(&deg[g * NN + dst], 1);
}

// --- 3-phase device-wide exclusive scan of deg -> E (E[g][0]=0, E[g][1+i]=start(i)) ---

__global__ __launch_bounds__(256) void scan_part(const int* __restrict__ deg, int* __restrict__ E,
                                                 int* __restrict__ part) {
    int b = blockIdx.x;
    int g = b / NCH, c = b - g * NCH;
    int t = threadIdx.x;
    int base = c * CH + t * 8;
    const int* dg = deg + g * NN;
    int v[8];
    int s = 0;
#pragma unroll
    for (int j = 0; j < 8; ++j) {
        int i = base + j;
        v[j] = (i < NN) ? dg[i] : 0;
        s += v[j];
    }
    __shared__ int sums[256];
    sums[t] = s;
    __syncthreads();
    for (int off = 1; off < 256; off <<= 1) {
        int x = (t >= off) ? sums[t - off] : 0;
        __syncthreads();
        sums[t] += x;
        __syncthreads();
    }
    int run = (t == 0) ? 0 : sums[t - 1];
    int* Eg = E + g * SM;
#pragma unroll
    for (int j = 0; j < 8; ++j) {
        int i = base + j;
        if (i < NN) Eg[1 + i] = run;
        run += v[j];
    }
    if (t == 255) part[g * NCH + c] = sums[255];
    if (c == 0 && t == 0) Eg[0] = 0;
}

__global__ __launch_bounds__(128) void scan_tops(int* __restrict__ part) {
    int g = blockIdx.x, t = threadIdx.x;
    __shared__ int s[128];
    int v = (t < NCH) ? part[g * NCH + t] : 0;
    s[t] = v;
    __syncthreads();
    for (int off = 1; off < 128; off <<= 1) {
        int x = (t >= off) ? s[t - off] : 0;
        __syncthreads();
        s[t] += x;
        __syncthreads();
    }
    if (t < NCH) part[g * NCH + t] = s[t] - v;  // exclusive
}

__global__ __launch_bounds__(256) void scan_add(const int* __restrict__ part, int* __restrict__ E) {
    int b = blockIdx.x;
    int g = b / NCH, c = b - g * NCH;
    int off = part[g * NCH + c];
    if (off == 0) return;  // uniform
    int t = threadIdx.x;
    int base = c * CH + t * 8;
    int* Eg = E + g * SM + 1;
#pragma unroll
    for (int j = 0; j < 8; ++j) {
        int i = base + j;
        if (i < NN) Eg[i] += off;
    }
}

__global__ __launch_bounds__(256) void place_kernel(const int* __restrict__ ei, int* __restrict__ E,
                                                    int* __restrict__ csr_src) {
    int idx = blockIdx.x * 256 + threadIdx.x;
    if (idx >= G * EE) return;
    int g = idx / EE, e = idx - g * EE;
    int src = ei[g * 2 * EE + e];
    int dst = ei[g * 2 * EE + EE + e];
    int pos = atomicAdd(&E[g * SM + 1 + dst], 1);
    csr_src[g * EE + pos] = src;
}

// ---------------- dtype prep ----------------

__global__ __launch_bounds__(256) void cast_x_kernel(const float* __restrict__ x, f16* __restrict__ o) {
    int i = blockIdx.x * 256 + threadIdx.x;
    float4 v = ((const float4*)x)[i];
    f16x4 h = {(f16)v.x, (f16)v.y, (f16)v.z, (f16)v.w};
    ((f16x4*)o)[i] = h;
}

// Wt[mat][n][k] = W[mat][k][n]  (fp16, transposed for MFMA B-operand)
__global__ __launch_bounds__(256) void cast_w_kernel(const float* __restrict__ Ws1, const float* __restrict__ Ws2,
                                                     f16* __restrict__ Wt) {
    int e = blockIdx.x * 256 + threadIdx.x;
    int mat = e >> 14, r = (e >> 7) & 127, c = e & 127;
    const float* src = (mat < 3) ? (Ws1 + mat * 16384) : (Ws2 + (mat - 3) * 16384);
    Wt[e] = (f16)src[c * 128 + r];
}

// ---------------- Fused GIN layer ----------------
// block = 64 nodes of one graph; 256 threads = 4 waves; wave-local LDS rows -> no barriers.
// LDS = 17.9 KiB, VGPR<=64 (launch_bounds 256,8) -> 8 blocks/CU = 32 waves/CU.
// r4 falsifier: wave-count concurrency is NOT the limiter. This round probes per-wave
// memory-level parallelism: gather unroll 4 (4 independent row loads in flight) with
// next-iteration CSR-index prefetch to hoist the index->row dependent chain.

__global__ __launch_bounds__(256, 8) void gin_layer(
    const f16* __restrict__ Xin, f16* __restrict__ Xout,
    const int* __restrict__ E, const int* __restrict__ csr_src,
    const f16* __restrict__ W1t, const f16* __restrict__ W2t,
    const float* __restrict__ b1, const float* __restrict__ b2,
    const float* __restrict__ lng, const float* __restrict__ lnb,
    int has_res, int do_read, float* __restrict__ gvec)
{
    __shared__ f16 A[64][136];    // gathered h tile; reused for y1, then store staging
    __shared__ float colsum[128];

    int t = threadIdx.x;
    // XCD-aware decode: grid = 8 * 391; slot = XCD, g = slot&3, bb covers [0,782)
    int slot = blockIdx.x & 7;
    int gi = blockIdx.x >> 3;           // 0..390
    int g = slot & 3;
    int bb = (slot >> 2) * 391 + gi;    // 0..781
    int nrow0 = bb * 64;
    long row0 = (long)g * NN + nrow0;
    int valid = min(64, NN - nrow0);

    if (do_read) {  // block-uniform arg; barrier is uniform
        if (t < 128) colsum[t] = 0.f;
        __syncthreads();
    }

    // ---- gather: 16 groups of 16 lanes, 4 rows each; f16x8 (16 B) per lane ----
    // wave w covers rows [16w, 16w+16) -> wave-local LDS writes.
    // unroll-4 + index prefetch: per main iteration, 4 independent 256-B row reads
    // in flight while the next 4 CSR indices load under the accumulate.
    {
        int grp = t >> 4, lane = t & 15;
        const int* rs = E + g * SM;
        const int* srcs = csr_src + (long)g * EE;
        long gbase = (long)g * NN * 16;  // in f16x8 units (16 per row)
        const f16x8* Xv = (const f16x8*)Xin;
#pragma unroll
        for (int i = 0; i < 4; ++i) {
            int r = grp * 4 + i;
            if (r < valid) {
                int n = nrow0 + r;
                f16x8 self = Xv[(row0 + r) * 16 + lane];
                float acc[8];
#pragma unroll
                for (int j = 0; j < 8; ++j) acc[j] = (float)self[j];
                int s0 = rs[n], s1 = rs[n + 1];
                int k = s0;
                // prefetch first 4 indices (guarded)
                int i0 = (k     < s1) ? srcs[k]     : 0;
                int i1 = (k + 1 < s1) ? srcs[k + 1] : 0;
                int i2 = (k + 2 < s1) ? srcs[k + 2] : 0;
                int i3 = (k + 3 < s1) ? srcs[k + 3] : 0;
                for (; k + 3 < s1; k += 4) {
                    f16x8 v0 = Xv[gbase + (long)i0 * 16 + lane];
                    f16x8 v1 = Xv[gbase + (long)i1 * 16 + lane];
                    f16x8 v2 = Xv[gbase + (long)i2 * 16 + lane];
                    f16x8 v3 = Xv[gbase + (long)i3 * 16 + lane];
                    // prefetch next 4 indices under the row-load latency
                    i0 = (k + 4 < s1) ? srcs[k + 4] : 0;
                    i1 = (k + 5 < s1) ? srcs[k + 5] : 0;
                    i2 = (k + 6 < s1) ? srcs[k + 6] : 0;
                    i3 = (k + 7 < s1) ? srcs[k + 7] : 0;
#pragma unroll
                    for (int j = 0; j < 8; ++j)
                        acc[j] += ((float)v0[j] + (float)v1[j]) + ((float)v2[j] + (float)v3[j]);
                }
                // tail (<=3 edges): indices already prefetched in i0..i2; issue together
                {
                    bool a0 = (k < s1), a1 = (k + 1 < s1), a2 = (k + 2 < s1);
                    f16x8 v0, v1, v2;
                    if (a0) v0 = Xv[gbase + (long)i0 * 16 + lane];
                    if (a1) v1 = Xv[gbase + (long)i1 * 16 + lane];
                    if (a2) v2 = Xv[gbase + (long)i2 * 16 + lane];
                    if (a0) {
#pragma unroll
                        for (int j = 0; j < 8; ++j) acc[j] += (float)v0[j];
                    }
                    if (a1) {
#pragma unroll
                        for (int j = 0; j < 8; ++j) acc[j] += (float)v1[j];
                    }
                    if (a2) {
#pragma unroll
                        for (int j = 0; j < 8; ++j) acc[j] += (float)v2[j];
                    }
                }
                f16x8 o;
#pragma unroll
                for (int j = 0; j < 8; ++j) o[j] = (f16)acc[j];
                *(f16x8*)&A[r][lane * 8] = o;
            } else {
                f16x8 z = {0, 0, 0, 0, 0, 0, 0, 0};
                *(f16x8*)&A[r][lane * 8] = z;
            }
        }
    }
    // no barrier: A rows are wave-local; same-wave DS ordering via lgkmcnt

    int w = t >> 6, l = t & 63, q = l >> 4, cl = l & 15;
    int mrow = w * 16 + cl;

    // ---- GEMM1: y1 = relu(A @ W1 + b1); B-fragments from global (L1/L2-resident) ----
    const f16x8* Wb1 = (const f16x8*)W1t + (cl * 16 + q);
    f32x4 acc[8];
#pragma unroll
    for (int ns = 0; ns < 8; ++ns) acc[ns] = (f32x4){0.f, 0.f, 0.f, 0.f};
#pragma unroll
    for (int kc = 0; kc < 4; ++kc) {
        f16x8 a = *(const f16x8*)&A[mrow][kc * 32 + q * 8];
#pragma unroll
        for (int ns = 0; ns < 8; ++ns) {
            f16x8 b = Wb1[ns * 256 + kc * 4];
            acc[ns] = __builtin_amdgcn_mfma_f32_16x16x32_f16(a, b, acc[ns], 0, 0, 0);
        }
    }

    // y1 -> A (wave-local rows, no cross-wave hazard)
#pragma unroll
    for (int ns = 0; ns < 8; ++ns) {
        float bv = b1[ns * 16 + cl];
#pragma unroll
        for (int r = 0; r < 4; ++r) {
            float v = fmaxf(acc[ns][r] + bv, 0.f);
            A[w * 16 + q * 4 + r][ns * 16 + cl] = (f16)v;
        }
    }

    // ---- GEMM2: y2 = y1 @ W2 + b2 (+ identity) ----
    const f16x8* Wb2 = (const f16x8*)W2t + (cl * 16 + q);
    f32x4 acc2[8];
#pragma unroll
    for (int ns = 0; ns < 8; ++ns) acc2[ns] = (f32x4){0.f, 0.f, 0.f, 0.f};
#pragma unroll
    for (int kc = 0; kc < 4; ++kc) {
        f16x8 a = *(const f16x8*)&A[mrow][kc * 32 + q * 8];
#pragma unroll
        for (int ns = 0; ns < 8; ++ns) {
            f16x8 b = Wb2[ns * 256 + kc * 4];
            acc2[ns] = __builtin_amdgcn_mfma_f32_16x16x32_f16(a, b, acc2[ns], 0, 0, 0);
        }
    }

    float o[8][4];
    float gm[8], gb[8];
#pragma unroll
    for (int ns = 0; ns < 8; ++ns) {
        int col = ns * 16 + cl;
        float b2v = b2[col];
        gm[ns] = lng[col];
        gb[ns] = lnb[col];
#pragma unroll
        for (int r = 0; r < 4; ++r) o[ns][r] = acc2[ns][r] + b2v;
    }
    if (has_res) {
        // identity from global Xin (L1/L2-warm from the gather's self-read)
#pragma unroll
        for (int r = 0; r < 4; ++r) {
            int lr = w * 16 + q * 4 + r;
            if (lr < valid) {
                const f16* xr = Xin + (row0 + lr) * 128 + cl;
#pragma unroll
                for (int ns = 0; ns < 8; ++ns) o[ns][r] += (float)xr[ns * 16];
            }
        }
    }

    // ---- LayerNorm per row (16 lanes of a q-group share a row) ----
#pragma unroll
    for (int r = 0; r < 4; ++r) {
        float s1 = 0.f, s2 = 0.f;
#pragma unroll
        for (int ns = 0; ns < 8; ++ns) { s1 += o[ns][r]; s2 += o[ns][r] * o[ns][r]; }
        s1 += __shfl_xor(s1, 1); s2 += __shfl_xor(s2, 1);
        s1 += __shfl_xor(s1, 2); s2 += __shfl_xor(s2, 2);
        s1 += __shfl_xor(s1, 4); s2 += __shfl_xor(s2, 4);
        s1 += __shfl_xor(s1, 8); s2 += __shfl_xor(s2, 8);
        float mean = s1 * (1.f / 128.f);
        float var = s2 * (1.f / 128.f) - mean * mean;
        float rstd = rsqrtf(var + LN_EPS);
#pragma unroll
        for (int ns = 0; ns < 8; ++ns) o[ns][r] = (o[ns][r] - mean) * rstd * gm[ns] + gb[ns];
    }

    if (!do_read) {
        // stage LN output in A (wave-local rows), then wave-local coalesced store
#pragma unroll
        for (int ns = 0; ns < 8; ++ns)
#pragma unroll
            for (int r = 0; r < 4; ++r)
                A[w * 16 + q * 4 + r][ns * 16 + cl] = (f16)o[ns][r];
        int rr = w * 16 + (l >> 2), seg = l & 3;
        if (rr < valid) {
            f16* dst = Xout + (row0 + rr) * 128 + seg * 32;
            const f16* srcp = &A[rr][seg * 32];
            *(f16x8*)(dst)      = *(const f16x8*)(srcp);
            *(f16x8*)(dst + 8)  = *(const f16x8*)(srcp + 8);
            *(f16x8*)(dst + 16) = *(const f16x8*)(srcp + 16);
            *(f16x8*)(dst + 24) = *(const f16x8*)(srcp + 24);
        }
    } else {
        // graph readout only (last layer): gvec[g] += column sums
#pragma unroll
        for (int ns = 0; ns < 8; ++ns) {
            float v = 0.f;
#pragma unroll
            for (int r = 0; r < 4; ++r) {
                int lr = w * 16 + q * 4 + r;
                if (lr < valid) v += o[ns][r];
            }
            v += __shfl_xor(v, 16);
            v += __shfl_xor(v, 32);
            if (l < 16) atomicAdd(&colsum[ns * 16 + cl], v);
        }
        __syncthreads();
        if (t < 128) atomicAdd(&gvec[g * 128 + t], colsum[t]);
    }
}

// ---------------- Attention pooling (single block) ----------------

__global__ __launch_bounds__(256) void att_kernel(const float* __restrict__ gvec, const float* __restrict__ w1,
                                                  const float* __restrict__ w2, float* __restrict__ out) {
    __shared__ float sup[64][4];
    __shared__ float att[8][4];
    int t = threadIdx.x;
    int ah = t >> 2, gg = t & 3;
    float d = 0.f;
    for (int k = 0; k < 128; ++k) d += w1[ah * 128 + k] * gvec[gg * 128 + k];
    sup[ah][gg] = tanhf(d);
    __syncthreads();
    if (t < 32) {
        int ne = t >> 2, g2 = t & 3;
        float sc = 0.f;
        for (int k = 0; k < 64; ++k) sc += w2[ne * 64 + k] * sup[k][g2];
        att[ne][g2] = sc;
    }
    __syncthreads();
    if (t < 8) {
        float m = fmaxf(fmaxf(att[t][0], att[t][1]), fmaxf(att[t][2], att[t][3]));
        float e0 = expf(att[t][0] - m), e1 = expf(att[t][1] - m);
        float e2 = expf(att[t][2] - m), e3 = expf(att[t][3] - m);
        float inv = 1.f / (e0 + e1 + e2 + e3);
        att[t][0] = e0 * inv; att[t][1] = e1 * inv; att[t][2] = e2 * inv; att[t][3] = e3 * inv;
    }
    __syncthreads();
    for (int o = t; o < 1024; o += 256) {
        int ne = o >> 7, dd = o & 127;
        float v = 0.f;
        for (int g2 = 0; g2 < 4; ++g2) v += att[ne][g2] * gvec[g2 * 128 + dd];
        out[o] = v;
    }
}

// ---------------- launch ----------------

extern "C" void kernel_launch(void* const* d_in, const int* in_sizes, int n_in,
                              void* d_out, int out_size, void* d_ws, size_t ws_size,
                              hipStream_t stream) {
    const float* x   = (const float*)d_in[0];
    const int*   ei  = (const int*)d_in[1];
    const float* Ws1 = (const float*)d_in[3];
    const float* bs1 = (const float*)d_in[4];
    const float* Ws2 = (const float*)d_in[5];
    const float* bs2 = (const float*)d_in[6];
    const float* lng = (const float*)d_in[7];
    const float* lnb = (const float*)d_in[8];
    const float* aw1 = (const float*)d_in[9];
    const float* aw2 = (const float*)d_in[10];

    char* ws = (char*)d_ws;
    f16*   XA       = (f16*)(ws);                      //  51,200,000 B
    f16*   XB       = (f16*)(ws + 51200000);           //  51,200,000 B
    int*   csr_src  = (int*)(ws + 102400000);          //   6,400,000 B
    int*   E        = (int*)(ws + 108800000);          //     800,128 B (G*SM ints)
    f16*   Wt       = (f16*)(ws + 109600256);          //     196,608 B
    float* gvec     = (float*)(ws + 109796864);        //       2,048 B
    int*   part     = (int*)(ws + 109798912);          //         400 B (G*NCH ints)
    // deg is dead before the first gin_layer writes XB -> overlay it there
    int*   deg      = (int*)(ws + 51200000);           //     800,000 B (overlaid on XB)

    hipMemsetAsync(deg, 0, G * NN * sizeof(int), stream);
    hipMemsetAsync(gvec, 0, G * D * sizeof(float), stream);

    hist_kernel<<<(G * EE + 255) / 256, 256, 0, stream>>>(ei, deg);
    scan_part<<<G * NCH, 256, 0, stream>>>(deg, E, part);
    scan_tops<<<G, 128, 0, stream>>>(part);
    scan_add<<<G * NCH, 256, 0, stream>>>(part, E);
    place_kernel<<<(G * EE + 255) / 256, 256, 0, stream>>>(ei, E, csr_src);

    cast_x_kernel<<<(G * NN * D / 4) / 256, 256, 0, stream>>>(x, XA);
    cast_w_kernel<<<(6 * D * D) / 256, 256, 0, stream>>>(Ws1, Ws2, Wt);

    f16* Xcur = XA;
    f16* Xnxt = XB;
    for (int l = 0; l < 3; ++l) {
        gin_layer<<<G * BPG, 256, 0, stream>>>(Xcur, Xnxt, E, csr_src,
                                               Wt + l * D * D, Wt + (3 + l) * D * D,
                                               bs1 + l * D, bs2 + l * D,
                                               lng + l * D, lnb + l * D,
                                               (l < 2) ? 1 : 0, (l == 2) ? 1 : 0, gvec);
        f16* tmp = Xcur; Xcur = Xnxt; Xnxt = tmp;
    }
    att_kernel<<<1, 256, 0, stream>>>(gvec, aw1, aw2, (float*)d_out);
}

// Round 6
// 867.397 us; speedup vs baseline: 1.0750x; 1.0750x over previous
//
#include <hip/hip_runtime.h>
#include <math.h>

#define G 4
#define NN 50000
#define EE 400000
#define D 128
#define LN_EPS 1e-5f
#define BPG 782    // blocks per graph (782*64 >= 50000)
#define SM 50008   // per-graph stride of E array in ints (NN+1 padded to 8)
#define CH 2048    // scan chunk (entries per block)
#define NCH ((NN + CH - 1) / CH)  // 25 chunks per graph

// fat prep kernel block ranges
#define FB_CASTX 25000   // G*NN*D/4/256
#define FB_CASTW (FB_CASTX + 384)      // 6*D*D/256
#define FB_HIST  (FB_CASTW + 6250)     // G*EE/256
#define FB_TOTAL (FB_HIST + 1)         // +1 block: gvec zero

typedef _Float16 f16;
typedef _Float16 f16x4 __attribute__((ext_vector_type(4)));
typedef _Float16 f16x8 __attribute__((ext_vector_type(8)));
typedef float f32x4 __attribute__((ext_vector_type(4)));

// ---------------- fused prep: cast_x || cast_w || hist || gvec zero ----------------

__global__ __launch_bounds__(256) void prep_fat(const float* __restrict__ x,
                                                const float* __restrict__ Ws1, const float* __restrict__ Ws2,
                                                const int* __restrict__ ei,
                                                f16* __restrict__ XA, f16* __restrict__ Wt,
                                                int* __restrict__ deg, float* __restrict__ gvec) {
    int b = blockIdx.x, t = threadIdx.x;
    if (b < FB_CASTX) {
        int i = b * 256 + t;
        float4 v = ((const float4*)x)[i];
        f16x4 h = {(f16)v.x, (f16)v.y, (f16)v.z, (f16)v.w};
        ((f16x4*)XA)[i] = h;
    } else if (b < FB_CASTW) {
        int e = (b - FB_CASTX) * 256 + t;
        int mat = e >> 14, r = (e >> 7) & 127, c = e & 127;
        const float* src = (mat < 3) ? (Ws1 + mat * 16384) : (Ws2 + (mat - 3) * 16384);
        Wt[e] = (f16)src[c * 128 + r];
    } else if (b < FB_HIST) {
        int idx = (b - FB_CASTW) * 256 + t;
        if (idx < G * EE) {
            int g = idx / EE, e = idx - g * EE;
            int dst = ei[g * 2 * EE + EE + e];
            atomicAdd(&deg[g * NN + dst], 1);
        }
    } else {
        gvec[t] = 0.f;
        gvec[256 + t] = 0.f;
    }
}

// --- 2-phase device-wide exclusive scan of deg -> E (E[g][0]=0, E[g][1+i]=start(i)) ---

__global__ __launch_bounds__(256) void scan_part(const int* __restrict__ deg, int* __restrict__ E,
                                                 int* __restrict__ part) {
    int b = blockIdx.x;
    int g = b / NCH, c = b - g * NCH;
    int t = threadIdx.x;
    int base = c * CH + t * 8;
    const int* dg = deg + g * NN;
    int v[8];
    int s = 0;
#pragma unroll
    for (int j = 0; j < 8; ++j) {
        int i = base + j;
        v[j] = (i < NN) ? dg[i] : 0;
        s += v[j];
    }
    __shared__ int sums[256];
    sums[t] = s;
    __syncthreads();
    for (int off = 1; off < 256; off <<= 1) {
        int x = (t >= off) ? sums[t - off] : 0;
        __syncthreads();
        sums[t] += x;
        __syncthreads();
    }
    int run = (t == 0) ? 0 : sums[t - 1];
    int* Eg = E + g * SM;
#pragma unroll
    for (int j = 0; j < 8; ++j) {
        int i = base + j;
        if (i < NN) Eg[1 + i] = run;
        run += v[j];
    }
    if (t == 255) part[g * NCH + c] = sums[255];  // raw chunk total
    if (c == 0 && t == 0) Eg[0] = 0;
}

// scan_add with the 25-entry top-level prefix computed locally (fuses old scan_tops)
__global__ __launch_bounds__(256) void scan_addtops(const int* __restrict__ part, int* __restrict__ E) {
    int b = blockIdx.x;
    int g = b / NCH, c = b - g * NCH;
    int t = threadIdx.x;
    __shared__ int sp[NCH];
    if (t < NCH) sp[t] = part[g * NCH + t];
    __syncthreads();
    int off = 0;
    for (int j = 0; j < c; ++j) off += sp[j];  // uniform, c <= 24
    if (off == 0) return;  // c==0 -> uniform early exit
    int base = c * CH + t * 8;
    int* Eg = E + g * SM + 1;
#pragma unroll
    for (int j = 0; j < 8; ++j) {
        int i = base + j;
        if (i < NN) Eg[i] += off;
    }
}

__global__ __launch_bounds__(256) void place_kernel(const int* __restrict__ ei, int* __restrict__ E,
                                                    int* __restrict__ csr_src) {
    int idx = blockIdx.x * 256 + threadIdx.x;
    if (idx >= G * EE) return;
    int g = idx / EE, e = idx - g * EE;
    int src = ei[g * 2 * EE + e];
    int dst = ei[g * 2 * EE + EE + e];
    int pos = atomicAdd(&E[g * SM + 1 + dst], 1);
    csr_src[g * EE + pos] = src;
}

// ---------------- Fused GIN layer ----------------
// block = 64 nodes of one graph; 256 threads = 4 waves; wave-local LDS rows -> no barriers.
// Gather = unroll-2 (r1/r4 known-good; r5's unroll-4 masked tail spilled to scratch: WRITE_SIZE
// 36->206 MB, dur +7%). ID tile restored (r1: 185us @ 16 waves beat r4's no-ID 190us @ 32 waves;
// occupancy beyond 16 waves measured worthless -> spend LDS, not global re-reads, on the residual).

__global__ __launch_bounds__(256, 4) void gin_layer(
    const f16* __restrict__ Xin, f16* __restrict__ Xout,
    const int* __restrict__ E, const int* __restrict__ csr_src,
    const f16* __restrict__ W1t, const f16* __restrict__ W2t,
    const float* __restrict__ b1, const float* __restrict__ b2,
    const float* __restrict__ lng, const float* __restrict__ lnb,
    int has_res, int do_read, float* __restrict__ gvec)
{
    __shared__ f16 A[64][136];    // gathered h tile; reused for y1, then store staging
    __shared__ f16 ID[64][136];   // identity (self) tile for residual
    __shared__ float colsum[128];

    int t = threadIdx.x;
    // XCD-aware decode: grid = 8 * 391; slot = XCD, g = slot&3, bb covers [0,782)
    int slot = blockIdx.x & 7;
    int gi = blockIdx.x >> 3;           // 0..390
    int g = slot & 3;
    int bb = (slot >> 2) * 391 + gi;    // 0..781
    int nrow0 = bb * 64;
    long row0 = (long)g * NN + nrow0;
    int valid = min(64, NN - nrow0);

    if (do_read) {  // block-uniform arg; barrier is uniform
        if (t < 128) colsum[t] = 0.f;
        __syncthreads();
    }

    // ---- gather: 16 groups of 16 lanes, 4 rows each; f16x8 (16 B) per lane ----
    // wave w covers rows [16w, 16w+16) -> wave-local LDS writes.
    {
        int grp = t >> 4, lane = t & 15;
        const int* rs = E + g * SM;
        const int* srcs = csr_src + (long)g * EE;
        long gbase = (long)g * NN * 16;  // in f16x8 units (16 per row)
        const f16x8* Xv = (const f16x8*)Xin;
#pragma unroll
        for (int i = 0; i < 4; ++i) {
            int r = grp * 4 + i;
            if (r < valid) {
                int n = nrow0 + r;
                f16x8 self = Xv[(row0 + r) * 16 + lane];
                if (has_res) *(f16x8*)&ID[r][lane * 8] = self;
                float acc[8];
#pragma unroll
                for (int j = 0; j < 8; ++j) acc[j] = (float)self[j];
                int s0 = rs[n], s1 = rs[n + 1];
                int k = s0;
                for (; k + 1 < s1; k += 2) {
                    f16x8 v0 = Xv[gbase + (long)srcs[k] * 16 + lane];
                    f16x8 v1 = Xv[gbase + (long)srcs[k + 1] * 16 + lane];
#pragma unroll
                    for (int j = 0; j < 8; ++j) acc[j] += (float)v0[j] + (float)v1[j];
                }
                if (k < s1) {
                    f16x8 v0 = Xv[gbase + (long)srcs[k] * 16 + lane];
#pragma unroll
                    for (int j = 0; j < 8; ++j) acc[j] += (float)v0[j];
                }
                f16x8 o;
#pragma unroll
                for (int j = 0; j < 8; ++j) o[j] = (f16)acc[j];
                *(f16x8*)&A[r][lane * 8] = o;
            } else {
                f16x8 z = {0, 0, 0, 0, 0, 0, 0, 0};
                *(f16x8*)&A[r][lane * 8] = z;
            }
        }
    }
    // no barrier: A/ID rows are wave-local; same-wave DS ordering via lgkmcnt

    int w = t >> 6, l = t & 63, q = l >> 4, cl = l & 15;
    int mrow = w * 16 + cl;

    // ---- GEMM1: y1 = relu(A @ W1 + b1); B-fragments from global (L1/L2-resident) ----
    const f16x8* Wb1 = (const f16x8*)W1t + (cl * 16 + q);
    f32x4 acc[8];
#pragma unroll
    for (int ns = 0; ns < 8; ++ns) acc[ns] = (f32x4){0.f, 0.f, 0.f, 0.f};
#pragma unroll
    for (int kc = 0; kc < 4; ++kc) {
        f16x8 a = *(const f16x8*)&A[mrow][kc * 32 + q * 8];
#pragma unroll
        for (int ns = 0; ns < 8; ++ns) {
            f16x8 b = Wb1[ns * 256 + kc * 4];
            acc[ns] = __builtin_amdgcn_mfma_f32_16x16x32_f16(a, b, acc[ns], 0, 0, 0);
        }
    }

    // y1 -> A (wave-local rows, no cross-wave hazard)
#pragma unroll
    for (int ns = 0; ns < 8; ++ns) {
        float bv = b1[ns * 16 + cl];
#pragma unroll
        for (int r = 0; r < 4; ++r) {
            float v = fmaxf(acc[ns][r] + bv, 0.f);
            A[w * 16 + q * 4 + r][ns * 16 + cl] = (f16)v;
        }
    }

    // ---- GEMM2: y2 = y1 @ W2 + b2 (+ identity) ----
    const f16x8* Wb2 = (const f16x8*)W2t + (cl * 16 + q);
    f32x4 acc2[8];
#pragma unroll
    for (int ns = 0; ns < 8; ++ns) acc2[ns] = (f32x4){0.f, 0.f, 0.f, 0.f};
#pragma unroll
    for (int kc = 0; kc < 4; ++kc) {
        f16x8 a = *(const f16x8*)&A[mrow][kc * 32 + q * 8];
#pragma unroll
        for (int ns = 0; ns < 8; ++ns) {
            f16x8 b = Wb2[ns * 256 + kc * 4];
            acc2[ns] = __builtin_amdgcn_mfma_f32_16x16x32_f16(a, b, acc2[ns], 0, 0, 0);
        }
    }

    float o[8][4];
    float gm[8], gb[8];
#pragma unroll
    for (int ns = 0; ns < 8; ++ns) {
        int col = ns * 16 + cl;
        float b2v = b2[col];
        gm[ns] = lng[col];
        gb[ns] = lnb[col];
#pragma unroll
        for (int r = 0; r < 4; ++r) o[ns][r] = acc2[ns][r] + b2v;
    }
    if (has_res) {
#pragma unroll
        for (int r = 0; r < 4; ++r) {
            int lr = w * 16 + q * 4 + r;
#pragma unroll
            for (int ns = 0; ns < 8; ++ns) o[ns][r] += (float)ID[lr][ns * 16 + cl];
        }
    }

    // ---- LayerNorm per row (16 lanes of a q-group share a row) ----
#pragma unroll
    for (int r = 0; r < 4; ++r) {
        float s1 = 0.f, s2 = 0.f;
#pragma unroll
        for (int ns = 0; ns < 8; ++ns) { s1 += o[ns][r]; s2 += o[ns][r] * o[ns][r]; }
        s1 += __shfl_xor(s1, 1); s2 += __shfl_xor(s2, 1);
        s1 += __shfl_xor(s1, 2); s2 += __shfl_xor(s2, 2);
        s1 += __shfl_xor(s1, 4); s2 += __shfl_xor(s2, 4);
        s1 += __shfl_xor(s1, 8); s2 += __shfl_xor(s2, 8);
        float mean = s1 * (1.f / 128.f);
        float var = s2 * (1.f / 128.f) - mean * mean;
        float rstd = rsqrtf(var + LN_EPS);
#pragma unroll
        for (int ns = 0; ns < 8; ++ns) o[ns][r] = (o[ns][r] - mean) * rstd * gm[ns] + gb[ns];
    }

    if (!do_read) {
        // stage LN output in A (wave-local rows), then wave-local coalesced store
#pragma unroll
        for (int ns = 0; ns < 8; ++ns)
#pragma unroll
            for (int r = 0; r < 4; ++r)
                A[w * 16 + q * 4 + r][ns * 16 + cl] = (f16)o[ns][r];
        int rr = w * 16 + (l >> 2), seg = l & 3;
        if (rr < valid) {
            f16* dst = Xout + (row0 + rr) * 128 + seg * 32;
            const f16* srcp = &A[rr][seg * 32];
            *(f16x8*)(dst)      = *(const f16x8*)(srcp);
            *(f16x8*)(dst + 8)  = *(const f16x8*)(srcp + 8);
            *(f16x8*)(dst + 16) = *(const f16x8*)(srcp + 16);
            *(f16x8*)(dst + 24) = *(const f16x8*)(srcp + 24);
        }
    } else {
        // graph readout only (last layer): gvec[g] += column sums
#pragma unroll
        for (int ns = 0; ns < 8; ++ns) {
            float v = 0.f;
#pragma unroll
            for (int r = 0; r < 4; ++r) {
                int lr = w * 16 + q * 4 + r;
                if (lr < valid) v += o[ns][r];
            }
            v += __shfl_xor(v, 16);
            v += __shfl_xor(v, 32);
            if (l < 16) atomicAdd(&colsum[ns * 16 + cl], v);
        }
        __syncthreads();
        if (t < 128) atomicAdd(&gvec[g * 128 + t], colsum[t]);
    }
}

// ---------------- Attention pooling (single block) ----------------

__global__ __launch_bounds__(256) void att_kernel(const float* __restrict__ gvec, const float* __restrict__ w1,
                                                  const float* __restrict__ w2, float* __restrict__ out) {
    __shared__ float sup[64][4];
    __shared__ float att[8][4];
    int t = threadIdx.x;
    int ah = t >> 2, gg = t & 3;
    float d = 0.f;
    for (int k = 0; k < 128; ++k) d += w1[ah * 128 + k] * gvec[gg * 128 + k];
    sup[ah][gg] = tanhf(d);
    __syncthreads();
    if (t < 32) {
        int ne = t >> 2, g2 = t & 3;
        float sc = 0.f;
        for (int k = 0; k < 64; ++k) sc += w2[ne * 64 + k] * sup[k][g2];
        att[ne][g2] = sc;
    }
    __syncthreads();
    if (t < 8) {
        float m = fmaxf(fmaxf(att[t][0], att[t][1]), fmaxf(att[t][2], att[t][3]));
        float e0 = expf(att[t][0] - m), e1 = expf(att[t][1] - m);
        float e2 = expf(att[t][2] - m), e3 = expf(att[t][3] - m);
        float inv = 1.f / (e0 + e1 + e2 + e3);
        att[t][0] = e0 * inv; att[t][1] = e1 * inv; att[t][2] = e2 * inv; att[t][3] = e3 * inv;
    }
    __syncthreads();
    for (int o = t; o < 1024; o += 256) {
        int ne = o >> 7, dd = o & 127;
        float v = 0.f;
        for (int g2 = 0; g2 < 4; ++g2) v += att[ne][g2] * gvec[g2 * 128 + dd];
        out[o] = v;
    }
}

// ---------------- launch ----------------

extern "C" void kernel_launch(void* const* d_in, const int* in_sizes, int n_in,
                              void* d_out, int out_size, void* d_ws, size_t ws_size,
                              hipStream_t stream) {
    const float* x   = (const float*)d_in[0];
    const int*   ei  = (const int*)d_in[1];
    const float* Ws1 = (const float*)d_in[3];
    const float* bs1 = (const float*)d_in[4];
    const float* Ws2 = (const float*)d_in[5];
    const float* bs2 = (const float*)d_in[6];
    const float* lng = (const float*)d_in[7];
    const float* lnb = (const float*)d_in[8];
    const float* aw1 = (const float*)d_in[9];
    const float* aw2 = (const float*)d_in[10];

    char* ws = (char*)d_ws;
    f16*   XA       = (f16*)(ws);                      //  51,200,000 B
    f16*   XB       = (f16*)(ws + 51200000);           //  51,200,000 B
    int*   csr_src  = (int*)(ws + 102400000);          //   6,400,000 B
    int*   E        = (int*)(ws + 108800000);          //     800,128 B (G*SM ints)
    f16*   Wt       = (f16*)(ws + 109600256);          //     196,608 B
    float* gvec     = (float*)(ws + 109796864);        //       2,048 B
    int*   part     = (int*)(ws + 109798912);          //         400 B (G*NCH ints)
    // deg is dead before the first gin_layer writes XB -> overlay it there
    int*   deg      = (int*)(ws + 51200000);           //     800,000 B (overlaid on XB)

    hipMemsetAsync(deg, 0, G * NN * sizeof(int), stream);

    // fused prep: cast_x || cast_w || hist || gvec zero (independent work, one dispatch)
    prep_fat<<<FB_TOTAL, 256, 0, stream>>>(x, Ws1, Ws2, ei, XA, Wt, deg, gvec);

    scan_part<<<G * NCH, 256, 0, stream>>>(deg, E, part);
    scan_addtops<<<G * NCH, 256, 0, stream>>>(part, E);
    place_kernel<<<(G * EE + 255) / 256, 256, 0, stream>>>(ei, E, csr_src);

    f16* Xcur = XA;
    f16* Xnxt = XB;
    for (int l = 0; l < 3; ++l) {
        gin_layer<<<G * BPG, 256, 0, stream>>>(Xcur, Xnxt, E, csr_src,
                                               Wt + l * D * D, Wt + (3 + l) * D * D,
                                               bs1 + l * D, bs2 + l * D,
                                               lng + l * D, lnb + l * D,
                                               (l < 2) ? 1 : 0, (l == 2) ? 1 : 0, gvec);
        f16* tmp = Xcur; Xcur = Xnxt; Xnxt = tmp;
    }
    att_kernel<<<1, 256, 0, stream>>>(gvec, aw1, aw2, (float*)d_out);
}